// Round 6
// baseline (114.883 us; speedup 1.0000x reference)
//
#include <hip/hip_runtime.h>
#include <stdint.h>

// Problem constants (TransformerLayer: N=6144, D=512, B=16, NMAX=512, H=8, HD=64)
#define N_NODES 6144
#define DIM 512
#define NGRAPH 16
#define NHEAD 8
#define EPSV 1e-5f

typedef unsigned short u16;
typedef short s16x4 __attribute__((ext_vector_type(4)));
typedef short s16x8 __attribute__((ext_vector_type(8)));
typedef __bf16 bf16x8 __attribute__((ext_vector_type(8)));
typedef float f32x4 __attribute__((ext_vector_type(4)));

__device__ __forceinline__ u16 f2bf(float f) {
  union { float f; unsigned u; } c{f};
  unsigned u = c.u;
  return (u16)((u + 0x7fffu + ((u >> 16) & 1u)) >> 16);  // RNE
}
__device__ __forceinline__ float bf2f(u16 v) {
  union { unsigned u; float f; } c{(unsigned)v << 16};
  return c.f;
}

__device__ __forceinline__ f32x4 mfma16(s16x8 a, s16x8 b, f32x4 c) {
  return __builtin_amdgcn_mfma_f32_16x16x32_bf16(
      __builtin_bit_cast(bf16x8, a), __builtin_bit_cast(bf16x8, b), c, 0, 0, 0);
}

__device__ __forceinline__ void gload_lds16(const void* g, void* l) {
  __builtin_amdgcn_global_load_lds(
      (const __attribute__((address_space(1))) unsigned int*)g,
      (__attribute__((address_space(3))) unsigned int*)l, 16, 0, 0);
}

// HW transpose read: lane reads 4 u16 at byte offsets {0,32,64,96} from its own
// addr (no internal lane offset); offset:128 walks to the next [4][16] subtile.
__device__ __forceinline__ s16x8 v_frag_tr(const u16* base, int u16idx) {
  s16x4 lo, hi;
  const __attribute__((address_space(3))) u16* p =
      (const __attribute__((address_space(3))) u16*)(base + u16idx);
  asm volatile("ds_read_b64_tr_b16 %0, %2\n\t"
               "ds_read_b64_tr_b16 %1, %2 offset:128\n\t"
               "s_waitcnt lgkmcnt(0)"
               : "=&v"(lo), "=&v"(hi)
               : "v"(p)
               : "memory");
  __builtin_amdgcn_sched_barrier(0);
  s16x8 r;
  r[0] = lo[0]; r[1] = lo[1]; r[2] = lo[2]; r[3] = lo[3];
  r[4] = hi[0]; r[5] = hi[1]; r[6] = hi[2]; r[7] = hi[3];
  return r;
}

// ---------------------------------------------------------------- prep
// One kernel: starts search + all weight transposes (f32->bf16) + h->bf16.
// blocks: [0] starts | [1,769) Wq/Wk/Wv qkvperm | [769,1025) Wo operm
//         [1025,1537) W1 plain | [1537,2049) W2 plain | [2049,5121) cvt h
__global__ void prep_kernel(const float* __restrict__ h, const int* __restrict__ batch,
                            const float* __restrict__ Wq, const float* __restrict__ Wk,
                            const float* __restrict__ Wv, const float* __restrict__ Wo,
                            const float* __restrict__ W1, const float* __restrict__ W2,
                            u16* __restrict__ bt_qkv, u16* __restrict__ bt_o,
                            u16* __restrict__ bt_1, u16* __restrict__ bt_2,
                            u16* __restrict__ A0, int* __restrict__ starts) {
  __shared__ float tile[32][33];
  const int bid = blockIdx.x, tid = threadIdx.x;
  if (bid == 0) {
    int g = tid;
    if (g > NGRAPH) return;
    if (g == NGRAPH) { starts[g] = N_NODES; return; }
    int lo = 0, hi = N_NODES;
    while (lo < hi) { int mid = (lo + hi) >> 1; if (batch[mid] < g) lo = mid + 1; else hi = mid; }
    starts[g] = lo;
    return;
  }
  if (bid >= 2049) {  // cvt h -> bf16 (float4 per lane)
    int i = (bid - 2049) * 256 + tid;
    float4 v = ((const float4*)h)[i];
    ushort4 o = make_ushort4(f2bf(v.x), f2bf(v.y), f2bf(v.z), f2bf(v.w));
    ((ushort4*)A0)[i] = o;
    return;
  }
  const int tx = tid & 31, ty = tid >> 5;
  if (bid <= 768) {  // QKV: dst[v][k] = src[k][p(v)] via v(c) = ((c&7)<<6)|(c>>3)
    const int w = (bid - 1) >> 8;
    const float* src = (w == 0) ? Wq : (w == 1) ? Wk : Wv;
    u16* dst = bt_qkv + (size_t)w * 512 * 512;
    const int t = (bid - 1) & 255;
    const int c0 = (t & 15) * 32, r0 = (t >> 4) * 32;
#pragma unroll
    for (int i = 0; i < 32; i += 8) tile[ty + i][tx] = src[(size_t)(r0 + ty + i) * 512 + c0 + tx];
    __syncthreads();
#pragma unroll
    for (int i = 0; i < 32; i += 8) {
      int c = c0 + ty + i;
      int v = ((c & 7) << 6) | (c >> 3);
      dst[(size_t)v * 512 + r0 + tx] = f2bf(tile[tx][ty + i]);
    }
  } else if (bid <= 1024) {  // O: dst[j][c] = src[md(c)][j], md(c)=((c&63)<<3)|(c>>6)
    const int t = bid - 769;
    const int c0 = (t & 15) * 32, j0 = (t >> 4) * 32;
#pragma unroll
    for (int i = 0; i < 32; i += 8) {
      int c = c0 + ty + i;
      int md = ((c & 63) << 3) | (c >> 6);
      tile[ty + i][tx] = Wo[(size_t)md * 512 + j0 + tx];
    }
    __syncthreads();
#pragma unroll
    for (int i = 0; i < 32; i += 8)
      bt_o[(size_t)(j0 + ty + i) * 512 + c0 + tx] = f2bf(tile[tx][ty + i]);
  } else if (bid <= 1536) {  // W1 plain: R=512 C=1024
    const int t = bid - 1025;
    const int c0 = (t & 31) * 32, r0 = (t >> 5) * 32;
#pragma unroll
    for (int i = 0; i < 32; i += 8) tile[ty + i][tx] = W1[(size_t)(r0 + ty + i) * 1024 + c0 + tx];
    __syncthreads();
#pragma unroll
    for (int i = 0; i < 32; i += 8) bt_1[(size_t)(c0 + ty + i) * 512 + r0 + tx] = f2bf(tile[tx][ty + i]);
  } else {  // W2 plain: R=1024 C=512
    const int t = bid - 1537;
    const int c0 = (t & 15) * 32, r0 = (t >> 4) * 32;
#pragma unroll
    for (int i = 0; i < 32; i += 8) tile[ty + i][tx] = W2[(size_t)(r0 + ty + i) * 512 + c0 + tx];
    __syncthreads();
#pragma unroll
    for (int i = 0; i < 32; i += 8) bt_2[(size_t)(c0 + ty + i) * 1024 + r0 + tx] = f2bf(tile[tx][ty + i]);
  }
}

// ---------------------------------------------------------------- GEMM
// C[i][j] = sum_k A[i][k] * Bt[j][k]   (A,Bt bf16 row-major, acc fp32)
// BK=64 staged as two stacked BK=32 half-tiles (identical swizzle per half).
// 2-phase double-buffered K-loop (T3 minimum recipe): ds_read frags of buf[cur],
// issue STAGE(buf[cur^1], t+1), MFMA, one barrier per K-step.
// EPI 0: QKV -> oq/ok/ov [node][512] row-major (col v, bias via perm)
// EPI 1: x1b = bf16(acc + bias + resf)  + col partials (pre-BN1)   [BM=64 only]
// EPI 2: ob  = relu(acc + bias) bf16
// EPI 3: of  = acc + bias + bf2f(resb)  + col partials (pre-BN2)   [BM=64 only]
template <int BM, int BN, int EPI>
__global__ __launch_bounds__(256, 2) void gemm_kernel(
    const u16* __restrict__ A, const u16* __restrict__ Bt,
    const float* __restrict__ bias0, const float* __restrict__ bias1,
    const float* __restrict__ bias2, const float* __restrict__ resf,
    const u16* __restrict__ resb, float2* __restrict__ part,
    u16* __restrict__ oq, u16* __restrict__ ok, u16* __restrict__ ov,
    float* __restrict__ of, u16* __restrict__ ob, int M, int N, int K) {
  constexpr int NW_M = (BM >= 128) ? 2 : 1;
  constexpr int NW_N = 4 / NW_M;
  constexpr int WM = BM / NW_M, WN = BN / NW_N;
  constexpr int FM = WM / 16, FN = WN / 16;
  constexpr int ASZ = BM * 64, BSZ = BN * 64;
  __shared__ __align__(16) u16 As[2 * ASZ];
  __shared__ __align__(16) u16 Bs[2 * BSZ];
  const int tid = threadIdx.x;
  const int lane = tid & 63, wv = tid >> 6;
  const int wm = wv / NW_N, wn = wv % NW_N;
  const int row0 = blockIdx.y * BM, col0 = blockIdx.x * BN;

  f32x4 acc[FM][FN] = {};
  int a_off[FM], b_off[FN];
#pragma unroll
  for (int fm = 0; fm < FM; ++fm) {
    int r = wm * WM + fm * 16 + (lane & 15);
    a_off[fm] = r * 32 + (((lane >> 4) ^ ((r >> 1) & 3)) << 3);
  }
#pragma unroll
  for (int fn = 0; fn < FN; ++fn) {
    int r = wn * WN + fn * 16 + (lane & 15);
    b_off[fn] = r * 32 + (((lane >> 4) ^ ((r >> 1) & 3)) << 3);
  }

  auto stage = [&](int buf, int k0) {
#pragma unroll
    for (int is = 0; is < BM / 32; ++is) {  // stage A: two BK=32 halves stacked
      int s = is * 256 + tid;
      int kh = s / (BM * 4);
      int sh = s - kh * (BM * 4);
      int r = sh >> 2;
      int cl = (sh & 3) ^ ((r >> 1) & 3);  // pre-swizzled source (involution)
      gload_lds16(A + (size_t)(row0 + r) * K + k0 + kh * 32 + cl * 8,
                  (void*)(As + buf * ASZ + (size_t)(is * 256 + (tid & ~63)) * 8));
    }
#pragma unroll
    for (int is = 0; is < BN / 32; ++is) {
      int s = is * 256 + tid;
      int kh = s / (BN * 4);
      int sh = s - kh * (BN * 4);
      int r = sh >> 2;
      int cl = (sh & 3) ^ ((r >> 1) & 3);
      gload_lds16(Bt + (size_t)(col0 + r) * K + k0 + kh * 32 + cl * 8,
                  (void*)(Bs + buf * BSZ + (size_t)(is * 256 + (tid & ~63)) * 8));
    }
  };

  stage(0, 0);
  __syncthreads();
  const int nt = K >> 6;
  int cur = 0;
  for (int t = 0; t < nt; ++t) {
    // ds_read current buffer's fragments first (before next-tile vmem issue)
    s16x8 af[2][FM], bfv[2][FN];
#pragma unroll
    for (int kh = 0; kh < 2; ++kh) {
#pragma unroll
      for (int fm = 0; fm < FM; ++fm)
        af[kh][fm] = *(const s16x8*)(As + cur * ASZ + kh * (BM * 32) + a_off[fm]);
#pragma unroll
      for (int fn = 0; fn < FN; ++fn)
        bfv[kh][fn] = *(const s16x8*)(Bs + cur * BSZ + kh * (BN * 32) + b_off[fn]);
    }
    if (t + 1 < nt) stage(cur ^ 1, (t + 1) << 6);  // prefetch next tile
#pragma unroll
    for (int kh = 0; kh < 2; ++kh)
#pragma unroll
      for (int fm = 0; fm < FM; ++fm)
#pragma unroll
        for (int fn = 0; fn < FN; ++fn)
          acc[fm][fn] = mfma16(af[kh][fm], bfv[kh][fn], acc[fm][fn]);
    __syncthreads();  // drains stage (vmcnt0) + separates reads from overwrite
    cur ^= 1;
  }

  // epilogue: C elem (row=(lane>>4)*4+ii, col=lane&15) per 16x16 frag
  if constexpr (EPI == 0) {
    const int which = col0 >> 9;
    u16* dst = (which == 0) ? oq : (which == 1) ? ok : ov;
    const float* bias = (which == 0) ? bias0 : (which == 1) ? bias1 : bias2;
#pragma unroll
    for (int fn = 0; fn < FN; ++fn) {
      const int j = col0 + wn * WN + fn * 16 + (lane & 15);
      const int v = j & 511;
      const float bj = bias[((v & 63) << 3) | (v >> 6)];
#pragma unroll
      for (int fm = 0; fm < FM; ++fm) {
        const int ibase = row0 + wm * WM + fm * 16 + ((lane >> 4) << 2);
#pragma unroll
        for (int ii = 0; ii < 4; ++ii)
          dst[(size_t)(ibase + ii) * 512 + v] = f2bf(acc[fm][fn][ii] + bj);
      }
    }
  } else {
#pragma unroll
    for (int fn = 0; fn < FN; ++fn) {
      const int j = col0 + wn * WN + fn * 16 + (lane & 15);
      const float bj = bias0[j];
      float s = 0.f, q = 0.f;
#pragma unroll
      for (int fm = 0; fm < FM; ++fm) {
        const int ibase = row0 + wm * WM + fm * 16 + ((lane >> 4) << 2);
        if constexpr (EPI == 1) {
#pragma unroll
          for (int ii = 0; ii < 4; ++ii) {
            int i = ibase + ii;
            float val = acc[fm][fn][ii] + bj + resf[(size_t)i * N + j];
            ob[(size_t)i * N + j] = f2bf(val);
            s += val; q += val * val;
          }
        } else if constexpr (EPI == 2) {
#pragma unroll
          for (int ii = 0; ii < 4; ++ii) {
            int i = ibase + ii;
            float v = acc[fm][fn][ii] + bj;
            ob[(size_t)i * N + j] = f2bf(v > 0.f ? v : 0.f);
          }
        } else {
#pragma unroll
          for (int ii = 0; ii < 4; ++ii) {
            int i = ibase + ii;
            float val = acc[fm][fn][ii] + bj + bf2f(resb[(size_t)i * N + j]);
            of[(size_t)i * N + j] = val;
            s += val; q += val * val;
          }
        }
      }
      if constexpr (EPI == 1 || EPI == 3) {  // BM=64: wave covers all 64 block rows
        s += __shfl_xor(s, 16); s += __shfl_xor(s, 32);
        q += __shfl_xor(q, 16); q += __shfl_xor(q, 32);
        if ((lane >> 4) == 0) part[(size_t)blockIdx.y * 512 + j] = make_float2(s, q);
      }
    }
  }
}

// ---------------------------------------------------------------- attention
// out[n] = sum_m exp(K[n]·Q[m]/8) V[m] / sum_m exp(...)   (per graph b, head hh)
// Scores are O(1) -> no max subtraction needed. m>=nb masked to P=0.
// q/k/v all [node][h*64+f]; output av [node][h*64+f].
// V staged subtiled [fblk][mblk][4][16] for ds_read_b64_tr_b16 B-fragments.
__global__ __launch_bounds__(256, 2) void attn_kernel(
    const u16* __restrict__ qp, const u16* __restrict__ kp,
    const u16* __restrict__ vp, const int* __restrict__ starts,
    u16* __restrict__ av) {
  __shared__ __align__(16) u16 Qs[32 * 64];   // [m][f], 8-chunk XOR swizzle
  __shared__ __align__(16) u16 Vs[32 * 64];   // [fblk][mblk][4][16] subtiled
  __shared__ __align__(16) u16 Ps[4][512];    // per-wave P tile [16][32]
  const int idx = blockIdx.x;
  const int rb = idx & 7, hh = (idx >> 3) & 7, b = idx >> 6;
  const int base = starts[b], nb = starts[b + 1] - base;
  const int r0 = rb * 64;
  if (r0 >= nb) return;
  const int tid = threadIdx.x, lane = tid & 63, wv = tid >> 6;
  const int g = lane >> 4;
  const int rloc = r0 + wv * 16 + (lane & 15);
  const u16* krow = kp + (size_t)(base + rloc) * 512 + hh * 64 + (g << 3);
  s16x8 ak0 = *(const s16x8*)(krow);
  s16x8 ak1 = *(const s16x8*)(krow + 32);
  f32x4 acc_av[4] = {};
  float rs[4] = {0.f, 0.f, 0.f, 0.f};
  u16* Pw = Ps[wv];
  // V staging source (inverse of the subtiled layout; LDS dest stays linear)
  const int vm = ((tid & 63) >> 3) * 4 + ((tid >> 1) & 3);
  const int vf = wv * 16 + (tid & 1) * 8;

  for (int m0 = 0; m0 < nb; m0 += 32) {
    __syncthreads();
    {  // stage Q tile 32x64
      int r = tid >> 3, cl = (tid & 7) ^ (r & 7);
      gload_lds16(qp + (size_t)(base + m0 + r) * 512 + hh * 64 + cl * 8,
                  (void*)(Qs + (size_t)(tid & ~63) * 8));
    }
    {  // stage V tile subtiled: wave wv covers fblk=wv
      gload_lds16(vp + (size_t)(base + m0 + vm) * 512 + hh * 64 + vf,
                  (void*)(Vs + (size_t)(tid & ~63) * 8));
    }
    __syncthreads();
#pragma unroll
    for (int ch = 0; ch < 2; ++ch) {
      f32x4 s = {};
#pragma unroll
      for (int kc = 0; kc < 2; ++kc) {
        const int mr = ch * 16 + (lane & 15);
        const int chunk = kc * 4 + g;
        s16x8 bq = *(const s16x8*)(Qs + mr * 64 + ((chunk ^ (mr & 7)) << 3));
        s = mfma16(kc == 0 ? ak0 : ak1, bq, s);
      }
      const int mg = m0 + ch * 16 + (lane & 15);
      const bool valid = mg < nb;
      const int c = ch * 16 + (lane & 15);
#pragma unroll
      for (int ii = 0; ii < 4; ++ii) {
        float pv = valid ? __expf(s[ii] * 0.125f) : 0.f;
        rs[ii] += pv;
        const int r = (g << 2) + ii;
        Pw[r * 32 + (((c >> 3) ^ ((r >> 1) & 3)) << 3) + (c & 7)] = f2bf(pv);
      }
    }
    // P as A-fragment; V via HW transpose read (k=m in register direction)
    const int pr = lane & 15;
    s16x8 pa = *(const s16x8*)(Pw + pr * 32 + ((g ^ ((pr >> 1) & 3)) << 3));
#pragma unroll
    for (int fb = 0; fb < 4; ++fb) {
      s16x8 bv = v_frag_tr(Vs, fb * 512 + g * 128 + (lane & 15));
      acc_av[fb] = mfma16(pa, bv, acc_av[fb]);
    }
  }
#pragma unroll
  for (int ii = 0; ii < 4; ++ii) {
    float v = rs[ii];
    v += __shfl_xor(v, 1); v += __shfl_xor(v, 2);
    v += __shfl_xor(v, 4); v += __shfl_xor(v, 8);
    rs[ii] = 1.f / v;
  }
#pragma unroll
  for (int ii = 0; ii < 4; ++ii) {
    const int rl = r0 + wv * 16 + (g << 2) + ii;
    if (rl < nb) {
      const size_t node = base + rl;
#pragma unroll
      for (int fb = 0; fb < 4; ++fb) {
        const int f = fb * 16 + (lane & 15);
        av[node * 512 + hh * 64 + f] = f2bf(acc_av[fb][ii] * rs[ii]);
      }
    }
  }
}

// ---------------------------------------------------------------- batchnorm
// Parallel finalize: 16 blocks x 32 cols. Thread (rg=t>>5, lc=t&31) sums 12 of
// the 96 row-partials (unrolled, independent, coalesced), LDS-tree over rg.
__global__ void bn_fin_kernel(const float2* __restrict__ part, const float* __restrict__ g,
                              const float* __restrict__ be, float2* __restrict__ stats) {
  __shared__ float red_s[8][32];
  __shared__ float red_q[8][32];
  const int t = threadIdx.x;
  const int lc = t & 31, rg = t >> 5;
  const int c = blockIdx.x * 32 + lc;
  float s = 0.f, q = 0.f;
#pragma unroll
  for (int k = 0; k < 12; ++k) {
    float2 v = part[(size_t)(rg + 8 * k) * 512 + c];
    s += v.x; q += v.y;
  }
  red_s[rg][lc] = s; red_q[rg][lc] = q;
  __syncthreads();
  if (rg == 0) {
#pragma unroll
    for (int r = 1; r < 8; ++r) { s += red_s[r][lc]; q += red_q[r][lc]; }
    const float inv = 1.f / (float)N_NODES;
    float m = s * inv, var = q * inv - m * m;
    float sc = g[c] * rsqrtf(var + EPSV);
    stats[c] = make_float2(sc, be[c] - m * sc);
  }
}

// x1n = bf16(x1b * st.x + st.y), 8 elems/lane
__global__ void bn_apply_bf_kernel(const u16* __restrict__ x, const float2* __restrict__ stats,
                                   u16* __restrict__ o) {
  const int i = (blockIdx.x * 256 + threadIdx.x) * 8;
  s16x8 v = *(const s16x8*)(x + i);
  const int c0 = i & 511;
  s16x8 r;
#pragma unroll
  for (int t = 0; t < 8; ++t) {
    float2 st = stats[c0 + t];
    r[t] = (short)f2bf(bf2f((u16)v[t]) * st.x + st.y);
  }
  *(s16x8*)(o + i) = r;
}

__global__ void bn_apply_f32_kernel(float* __restrict__ x, const float2* __restrict__ stats) {
  const int i = (blockIdx.x * 256 + threadIdx.x) * 4;
  float4 v = *(float4*)(x + i);
  const int c = i & 511;
  float2 sa = stats[c], sb = stats[c + 1], sc2 = stats[c + 2], sd = stats[c + 3];
  *(float4*)(x + i) = make_float4(v.x * sa.x + sa.y, v.y * sb.x + sb.y,
                                  v.z * sc2.x + sc2.y, v.w * sd.x + sd.y);
}

// ---------------------------------------------------------------- launch
extern "C" void kernel_launch(void* const* d_in, const int* in_sizes, int n_in,
                              void* d_out, int out_size, void* d_ws, size_t ws_size,
                              hipStream_t stream) {
  const float* h   = (const float*)d_in[0];
  const int* batch = (const int*)d_in[1];
  const float* Wq = (const float*)d_in[2];  const float* bq = (const float*)d_in[3];
  const float* Wk = (const float*)d_in[4];  const float* bk = (const float*)d_in[5];
  const float* Wv = (const float*)d_in[6];  const float* bv = (const float*)d_in[7];
  const float* Wo = (const float*)d_in[8];  const float* bo = (const float*)d_in[9];
  const float* g1 = (const float*)d_in[10]; const float* be1 = (const float*)d_in[11];
  const float* W1 = (const float*)d_in[12]; const float* b1v = (const float*)d_in[13];
  const float* W2 = (const float*)d_in[14]; const float* b2v = (const float*)d_in[15];
  const float* g2 = (const float*)d_in[16]; const float* be2 = (const float*)d_in[17];
  float* out = (float*)d_out;
  (void)in_sizes; (void)n_in; (void)out_size; (void)ws_size;

  char* ws = (char*)d_ws;
  size_t off = 0;
  auto alloc = [&](size_t bytes) -> void* {
    void* p = ws + off;
    off += (bytes + 255) & ~(size_t)255;
    return p;
  };
  int*    starts = (int*)alloc(17 * 4);
  float2* part1  = (float2*)alloc((size_t)96 * 512 * sizeof(float2));
  float2* part2  = (float2*)alloc((size_t)96 * 512 * sizeof(float2));
  float2* stats1 = (float2*)alloc(512 * sizeof(float2));
  float2* stats2 = (float2*)alloc(512 * sizeof(float2));
  u16* bt_qkv = (u16*)alloc((size_t)1536 * 512 * 2);
  u16* bt_o   = (u16*)alloc((size_t)512 * 512 * 2);
  u16* bt_1   = (u16*)alloc((size_t)1024 * 512 * 2);
  u16* bt_2   = (u16*)alloc((size_t)512 * 1024 * 2);
  u16* A0  = (u16*)alloc((size_t)N_NODES * 512 * 2);          // h bf16; reused as av
  u16* qp  = (u16*)alloc((size_t)(N_NODES + 64) * 512 * 2);   // reused (with kp) as x2
  u16* kp  = (u16*)alloc((size_t)(N_NODES + 64) * 512 * 2);
  u16* vpb = (u16*)alloc((size_t)(N_NODES + 64) * 512 * 2);
  u16* x1b = (u16*)alloc((size_t)N_NODES * 512 * 2);          // pre-BN1 value (bf16)
  u16* x1n = (u16*)alloc((size_t)N_NODES * 512 * 2);          // normalized (bf16)
  u16* av = A0;
  u16* x2 = qp;  // qp+kp = 12.7MB >= 12.6MB needed

  prep_kernel<<<5121, 256, 0, stream>>>(h, batch, Wq, Wk, Wv, Wo, W1, W2,
                                        bt_qkv, bt_o, bt_1, bt_2, A0, starts);
  gemm_kernel<128, 128, 0><<<dim3(12, 48), 256, 0, stream>>>(
      A0, bt_qkv, bq, bk, bv, nullptr, nullptr, nullptr, qp, kp, vpb,
      nullptr, nullptr, N_NODES, 1536, 512);
  attn_kernel<<<NGRAPH * NHEAD * 8, 256, 0, stream>>>(qp, kp, vpb, starts, av);
  gemm_kernel<64, 128, 1><<<dim3(4, 96), 256, 0, stream>>>(
      av, bt_o, bo, nullptr, nullptr, h, nullptr, part1, nullptr, nullptr, nullptr,
      nullptr, x1b, N_NODES, 512, 512);
  bn_fin_kernel<<<16, 256, 0, stream>>>(part1, g1, be1, stats1);
  bn_apply_bf_kernel<<<1536, 256, 0, stream>>>(x1b, stats1, x1n);
  gemm_kernel<128, 128, 2><<<dim3(8, 48), 256, 0, stream>>>(
      x1n, bt_1, b1v, nullptr, nullptr, nullptr, nullptr, nullptr, nullptr, nullptr,
      nullptr, nullptr, x2, N_NODES, 1024, 512);
  gemm_kernel<64, 128, 3><<<dim3(4, 96), 256, 0, stream>>>(
      x2, bt_2, b2v, nullptr, nullptr, nullptr, x1n, part2, nullptr, nullptr, nullptr,
      out, nullptr, N_NODES, 512, 1024);
  bn_fin_kernel<<<16, 256, 0, stream>>>(part2, g2, be2, stats2);
  bn_apply_f32_kernel<<<3072, 256, 0, stream>>>(out, stats2);
}

// Round 7
// 113.767 us; speedup vs baseline: 1.0098x; 1.0098x over previous
//
#include <hip/hip_runtime.h>
#include <stdint.h>

// Problem constants (TransformerLayer: N=6144, D=512, B=16, NMAX=512, H=8, HD=64)
#define N_NODES 6144
#define DIM 512
#define NGRAPH 16
#define NHEAD 8
#define EPSV 1e-5f

typedef unsigned short u16;
typedef short s16x4 __attribute__((ext_vector_type(4)));
typedef short s16x8 __attribute__((ext_vector_type(8)));
typedef __bf16 bf16x8 __attribute__((ext_vector_type(8)));
typedef float f32x4 __attribute__((ext_vector_type(4)));

__device__ __forceinline__ u16 f2bf(float f) {
  union { float f; unsigned u; } c{f};
  unsigned u = c.u;
  return (u16)((u + 0x7fffu + ((u >> 16) & 1u)) >> 16);  // RNE
}
__device__ __forceinline__ float bf2f(u16 v) {
  union { unsigned u; float f; } c{(unsigned)v << 16};
  return c.f;
}

__device__ __forceinline__ f32x4 mfma16(s16x8 a, s16x8 b, f32x4 c) {
  return __builtin_amdgcn_mfma_f32_16x16x32_bf16(
      __builtin_bit_cast(bf16x8, a), __builtin_bit_cast(bf16x8, b), c, 0, 0, 0);
}

__device__ __forceinline__ void gload_lds16(const void* g, void* l) {
  __builtin_amdgcn_global_load_lds(
      (const __attribute__((address_space(1))) unsigned int*)g,
      (__attribute__((address_space(3))) unsigned int*)l, 16, 0, 0);
}

// HW transpose read: lane reads 4 u16 at byte offsets {0,32,64,96} from its own
// addr (no internal lane offset); offset:128 walks to the next [4][16] subtile.
__device__ __forceinline__ s16x8 v_frag_tr(const u16* base, int u16idx) {
  s16x4 lo, hi;
  const __attribute__((address_space(3))) u16* p =
      (const __attribute__((address_space(3))) u16*)(base + u16idx);
  asm volatile("ds_read_b64_tr_b16 %0, %2\n\t"
               "ds_read_b64_tr_b16 %1, %2 offset:128\n\t"
               "s_waitcnt lgkmcnt(0)"
               : "=&v"(lo), "=&v"(hi)
               : "v"(p)
               : "memory");
  __builtin_amdgcn_sched_barrier(0);
  s16x8 r;
  r[0] = lo[0]; r[1] = lo[1]; r[2] = lo[2]; r[3] = lo[3];
  r[4] = hi[0]; r[5] = hi[1]; r[6] = hi[2]; r[7] = hi[3];
  return r;
}

// ---------------------------------------------------------------- prep
// One kernel: starts search + all weight transposes (f32->bf16) + h->bf16.
// blocks: [0] starts | [1,769) Wq/Wk/Wv qkvperm | [769,1025) Wo operm
//         [1025,1537) W1 plain | [1537,2049) W2 plain | [2049,5121) cvt h
__global__ void prep_kernel(const float* __restrict__ h, const int* __restrict__ batch,
                            const float* __restrict__ Wq, const float* __restrict__ Wk,
                            const float* __restrict__ Wv, const float* __restrict__ Wo,
                            const float* __restrict__ W1, const float* __restrict__ W2,
                            u16* __restrict__ bt_qkv, u16* __restrict__ bt_o,
                            u16* __restrict__ bt_1, u16* __restrict__ bt_2,
                            u16* __restrict__ A0, int* __restrict__ starts) {
  __shared__ float tile[32][33];
  const int bid = blockIdx.x, tid = threadIdx.x;
  if (bid == 0) {
    int g = tid;
    if (g > NGRAPH) return;
    if (g == NGRAPH) { starts[g] = N_NODES; return; }
    int lo = 0, hi = N_NODES;
    while (lo < hi) { int mid = (lo + hi) >> 1; if (batch[mid] < g) lo = mid + 1; else hi = mid; }
    starts[g] = lo;
    return;
  }
  if (bid >= 2049) {  // cvt h -> bf16 (float4 per lane)
    int i = (bid - 2049) * 256 + tid;
    float4 v = ((const float4*)h)[i];
    ushort4 o = make_ushort4(f2bf(v.x), f2bf(v.y), f2bf(v.z), f2bf(v.w));
    ((ushort4*)A0)[i] = o;
    return;
  }
  const int tx = tid & 31, ty = tid >> 5;
  if (bid <= 768) {  // QKV: dst[v][k] = src[k][p(v)] via v(c) = ((c&7)<<6)|(c>>3)
    const int w = (bid - 1) >> 8;
    const float* src = (w == 0) ? Wq : (w == 1) ? Wk : Wv;
    u16* dst = bt_qkv + (size_t)w * 512 * 512;
    const int t = (bid - 1) & 255;
    const int c0 = (t & 15) * 32, r0 = (t >> 4) * 32;
#pragma unroll
    for (int i = 0; i < 32; i += 8) tile[ty + i][tx] = src[(size_t)(r0 + ty + i) * 512 + c0 + tx];
    __syncthreads();
#pragma unroll
    for (int i = 0; i < 32; i += 8) {
      int c = c0 + ty + i;
      int v = ((c & 7) << 6) | (c >> 3);
      dst[(size_t)v * 512 + r0 + tx] = f2bf(tile[tx][ty + i]);
    }
  } else if (bid <= 1024) {  // O: dst[j][c] = src[md(c)][j], md(c)=((c&63)<<3)|(c>>6)
    const int t = bid - 769;
    const int c0 = (t & 15) * 32, j0 = (t >> 4) * 32;
#pragma unroll
    for (int i = 0; i < 32; i += 8) {
      int c = c0 + ty + i;
      int md = ((c & 63) << 3) | (c >> 6);
      tile[ty + i][tx] = Wo[(size_t)md * 512 + j0 + tx];
    }
    __syncthreads();
#pragma unroll
    for (int i = 0; i < 32; i += 8)
      bt_o[(size_t)(j0 + ty + i) * 512 + c0 + tx] = f2bf(tile[tx][ty + i]);
  } else if (bid <= 1536) {  // W1 plain: R=512 C=1024
    const int t = bid - 1025;
    const int c0 = (t & 31) * 32, r0 = (t >> 5) * 32;
#pragma unroll
    for (int i = 0; i < 32; i += 8) tile[ty + i][tx] = W1[(size_t)(r0 + ty + i) * 1024 + c0 + tx];
    __syncthreads();
#pragma unroll
    for (int i = 0; i < 32; i += 8) bt_1[(size_t)(c0 + ty + i) * 512 + r0 + tx] = f2bf(tile[tx][ty + i]);
  } else {  // W2 plain: R=1024 C=512
    const int t = bid - 1537;
    const int c0 = (t & 15) * 32, r0 = (t >> 4) * 32;
#pragma unroll
    for (int i = 0; i < 32; i += 8) tile[ty + i][tx] = W2[(size_t)(r0 + ty + i) * 512 + c0 + tx];
    __syncthreads();
#pragma unroll
    for (int i = 0; i < 32; i += 8) bt_2[(size_t)(c0 + ty + i) * 1024 + r0 + tx] = f2bf(tile[tx][ty + i]);
  }
}

// ---------------------------------------------------------------- GEMM
// C[i][j] = sum_k A[i][k] * Bt[j][k]   (A,Bt bf16 row-major, acc fp32)
// BK=64 staged as two stacked BK=32 half-tiles (identical swizzle per half).
// EPI 0: QKV -> oq/ok/ov [node][512] row-major (col v, bias via perm; BN=192 ok)
// EPI 1: x1b = bf16(acc + bias + resf)            + col partials   [BM=64 only]
// EPI 2: ob  = relu(acc + bias) bf16
// EPI 3: of  = acc + bias + (bf2f(resb)*st.x+st.y) + col partials  [BM=64 only]
template <int BM, int BN, int EPI>
__global__ __launch_bounds__(256, 2) void gemm_kernel(
    const u16* __restrict__ A, const u16* __restrict__ Bt,
    const float* __restrict__ bias0, const float* __restrict__ bias1,
    const float* __restrict__ bias2, const float* __restrict__ resf,
    const u16* __restrict__ resb, const float2* __restrict__ stats,
    float2* __restrict__ part,
    u16* __restrict__ oq, u16* __restrict__ ok, u16* __restrict__ ov,
    float* __restrict__ of, u16* __restrict__ ob, int M, int N, int K) {
  constexpr int NW_M = (BM >= 128) ? 2 : 1;
  constexpr int NW_N = 4 / NW_M;
  constexpr int WM = BM / NW_M, WN = BN / NW_N;
  constexpr int FM = WM / 16, FN = WN / 16;
  __shared__ __align__(16) u16 As[BM * 64];
  __shared__ __align__(16) u16 Bs[BN * 64];
  const int tid = threadIdx.x;
  const int lane = tid & 63, wv = tid >> 6;
  const int wm = wv / NW_N, wn = wv % NW_N;
  const int row0 = blockIdx.y * BM, col0 = blockIdx.x * BN;

  f32x4 acc[FM][FN] = {};
  int a_off[FM], b_off[FN];
#pragma unroll
  for (int fm = 0; fm < FM; ++fm) {
    int r = wm * WM + fm * 16 + (lane & 15);
    a_off[fm] = r * 32 + (((lane >> 4) ^ ((r >> 1) & 3)) << 3);
  }
#pragma unroll
  for (int fn = 0; fn < FN; ++fn) {
    int r = wn * WN + fn * 16 + (lane & 15);
    b_off[fn] = r * 32 + (((lane >> 4) ^ ((r >> 1) & 3)) << 3);
  }

  for (int k0 = 0; k0 < K; k0 += 64) {
    __syncthreads();
#pragma unroll
    for (int is = 0; is < BM / 32; ++is) {  // stage A: two BK=32 halves stacked
      int s = is * 256 + tid;
      int kh = s / (BM * 4);
      int sh = s - kh * (BM * 4);
      int r = sh >> 2;
      int cl = (sh & 3) ^ ((r >> 1) & 3);  // pre-swizzled source (involution)
      gload_lds16(A + (size_t)(row0 + r) * K + k0 + kh * 32 + cl * 8,
                  (void*)(As + (size_t)(is * 256 + (tid & ~63)) * 8));
    }
#pragma unroll
    for (int is = 0; is < BN / 32; ++is) {
      int s = is * 256 + tid;
      int kh = s / (BN * 4);
      int sh = s - kh * (BN * 4);
      int r = sh >> 2;
      int cl = (sh & 3) ^ ((r >> 1) & 3);
      gload_lds16(Bt + (size_t)(col0 + r) * K + k0 + kh * 32 + cl * 8,
                  (void*)(Bs + (size_t)(is * 256 + (tid & ~63)) * 8));
    }
    __syncthreads();
#pragma unroll
    for (int kh = 0; kh < 2; ++kh) {
      s16x8 af[FM], bfv[FN];
#pragma unroll
      for (int fm = 0; fm < FM; ++fm) af[fm] = *(const s16x8*)(As + kh * (BM * 32) + a_off[fm]);
#pragma unroll
      for (int fn = 0; fn < FN; ++fn) bfv[fn] = *(const s16x8*)(Bs + kh * (BN * 32) + b_off[fn]);
#pragma unroll
      for (int fm = 0; fm < FM; ++fm)
#pragma unroll
        for (int fn = 0; fn < FN; ++fn)
          acc[fm][fn] = mfma16(af[fm], bfv[fn], acc[fm][fn]);
    }
  }

  // epilogue: C elem (row=(lane>>4)*4+ii, col=lane&15) per 16x16 frag
  if constexpr (EPI == 0) {
#pragma unroll
    for (int fn = 0; fn < FN; ++fn) {
      const int j = col0 + wn * WN + fn * 16 + (lane & 15);
      const int which = j >> 9;  // uniform per (wn,fn): 16-blocks never straddle 512
      u16* dst = (which == 0) ? oq : (which == 1) ? ok : ov;
      const float* bias = (which == 0) ? bias0 : (which == 1) ? bias1 : bias2;
      const int v = j & 511;
      const float bj = bias[((v & 63) << 3) | (v >> 6)];
#pragma unroll
      for (int fm = 0; fm < FM; ++fm) {
        const int ibase = row0 + wm * WM + fm * 16 + ((lane >> 4) << 2);
#pragma unroll
        for (int ii = 0; ii < 4; ++ii)
          dst[(size_t)(ibase + ii) * 512 + v] = f2bf(acc[fm][fn][ii] + bj);
      }
    }
  } else {
#pragma unroll
    for (int fn = 0; fn < FN; ++fn) {
      const int j = col0 + wn * WN + fn * 16 + (lane & 15);
      const float bj = bias0[j];
      float s = 0.f, q = 0.f;
#pragma unroll
      for (int fm = 0; fm < FM; ++fm) {
        const int ibase = row0 + wm * WM + fm * 16 + ((lane >> 4) << 2);
        if constexpr (EPI == 1) {
#pragma unroll
          for (int ii = 0; ii < 4; ++ii) {
            int i = ibase + ii;
            float val = acc[fm][fn][ii] + bj + resf[(size_t)i * N + j];
            ob[(size_t)i * N + j] = f2bf(val);
            s += val; q += val * val;
          }
        } else if constexpr (EPI == 2) {
#pragma unroll
          for (int ii = 0; ii < 4; ++ii) {
            int i = ibase + ii;
            float v = acc[fm][fn][ii] + bj;
            ob[(size_t)i * N + j] = f2bf(v > 0.f ? v : 0.f);
          }
        } else {
          const float2 st = stats[j];
#pragma unroll
          for (int ii = 0; ii < 4; ++ii) {
            int i = ibase + ii;
            float val = acc[fm][fn][ii] + bj + (bf2f(resb[(size_t)i * N + j]) * st.x + st.y);
            of[(size_t)i * N + j] = val;
            s += val; q += val * val;
          }
        }
      }
      if constexpr (EPI == 1 || EPI == 3) {  // BM=64: wave covers all 64 block rows
        s += __shfl_xor(s, 16); s += __shfl_xor(s, 32);
        q += __shfl_xor(q, 16); q += __shfl_xor(q, 32);
        if ((lane >> 4) == 0) part[(size_t)blockIdx.y * 512 + j] = make_float2(s, q);
      }
    }
  }
}

// ---------------------------------------------------------------- attention
// out[n] = sum_m exp(K[n]·Q[m]/8) V[m] / sum_m exp(...)   (per graph b, head hh)
// Scores are O(1) -> no max subtraction needed. m>=nb masked to P=0.
// q/k/v all [node][h*64+f]; output av [node][h*64+f].
// V staged subtiled [fblk][mblk][4][16] for ds_read_b64_tr_b16 B-fragments.
__global__ __launch_bounds__(256, 2) void attn_kernel(
    const u16* __restrict__ qp, const u16* __restrict__ kp,
    const u16* __restrict__ vp, const int* __restrict__ starts,
    u16* __restrict__ av) {
  __shared__ __align__(16) u16 Qs[32 * 64];   // [m][f], 8-chunk XOR swizzle
  __shared__ __align__(16) u16 Vs[32 * 64];   // [fblk][mblk][4][16] subtiled
  __shared__ __align__(16) u16 Ps[4][512];    // per-wave P tile [16][32]
  const int idx = blockIdx.x;
  const int rb = idx & 7, hh = (idx >> 3) & 7, b = idx >> 6;
  const int base = starts[b], nb = starts[b + 1] - base;
  const int r0 = rb * 64;
  if (r0 >= nb) return;
  const int tid = threadIdx.x, lane = tid & 63, wv = tid >> 6;
  const int g = lane >> 4;
  const int rloc = r0 + wv * 16 + (lane & 15);
  const u16* krow = kp + (size_t)(base + rloc) * 512 + hh * 64 + (g << 3);
  s16x8 ak0 = *(const s16x8*)(krow);
  s16x8 ak1 = *(const s16x8*)(krow + 32);
  f32x4 acc_av[4] = {};
  float rs[4] = {0.f, 0.f, 0.f, 0.f};
  u16* Pw = Ps[wv];
  // V staging source (inverse of the subtiled layout; LDS dest stays linear)
  const int vm = ((tid & 63) >> 3) * 4 + ((tid >> 1) & 3);
  const int vf = wv * 16 + (tid & 1) * 8;

  for (int m0 = 0; m0 < nb; m0 += 32) {
    __syncthreads();
    {  // stage Q tile 32x64
      int r = tid >> 3, cl = (tid & 7) ^ (r & 7);
      gload_lds16(qp + (size_t)(base + m0 + r) * 512 + hh * 64 + cl * 8,
                  (void*)(Qs + (size_t)(tid & ~63) * 8));
    }
    {  // stage V tile subtiled: wave wv covers fblk=wv
      gload_lds16(vp + (size_t)(base + m0 + vm) * 512 + hh * 64 + vf,
                  (void*)(Vs + (size_t)(tid & ~63) * 8));
    }
    __syncthreads();
#pragma unroll
    for (int ch = 0; ch < 2; ++ch) {
      f32x4 s = {};
#pragma unroll
      for (int kc = 0; kc < 2; ++kc) {
        const int mr = ch * 16 + (lane & 15);
        const int chunk = kc * 4 + g;
        s16x8 bq = *(const s16x8*)(Qs + mr * 64 + ((chunk ^ (mr & 7)) << 3));
        s = mfma16(kc == 0 ? ak0 : ak1, bq, s);
      }
      const int mg = m0 + ch * 16 + (lane & 15);
      const bool valid = mg < nb;
      const int c = ch * 16 + (lane & 15);
#pragma unroll
      for (int ii = 0; ii < 4; ++ii) {
        float pv = valid ? __expf(s[ii] * 0.125f) : 0.f;
        rs[ii] += pv;
        const int r = (g << 2) + ii;
        Pw[r * 32 + (((c >> 3) ^ ((r >> 1) & 3)) << 3) + (c & 7)] = f2bf(pv);
      }
    }
    // P as A-fragment; V via HW transpose read (k=m in register direction)
    const int pr = lane & 15;
    s16x8 pa = *(const s16x8*)(Pw + pr * 32 + ((g ^ ((pr >> 1) & 3)) << 3));
#pragma unroll
    for (int fb = 0; fb < 4; ++fb) {
      s16x8 bv = v_frag_tr(Vs, fb * 512 + g * 128 + (lane & 15));
      acc_av[fb] = mfma16(pa, bv, acc_av[fb]);
    }
  }
#pragma unroll
  for (int ii = 0; ii < 4; ++ii) {
    float v = rs[ii];
    v += __shfl_xor(v, 1); v += __shfl_xor(v, 2);
    v += __shfl_xor(v, 4); v += __shfl_xor(v, 8);
    rs[ii] = 1.f / v;
  }
#pragma unroll
  for (int ii = 0; ii < 4; ++ii) {
    const int rl = r0 + wv * 16 + (g << 2) + ii;
    if (rl < nb) {
      const size_t node = base + rl;
#pragma unroll
      for (int fb = 0; fb < 4; ++fb) {
        const int f = fb * 16 + (lane & 15);
        av[node * 512 + hh * 64 + f] = f2bf(acc_av[fb][ii] * rs[ii]);
      }
    }
  }
}

// ---------------------------------------------------------------- batchnorm
// Parallel finalize: 16 blocks x 32 cols. Thread (rg=t>>5, lc=t&31) sums 12 of
// the 96 row-partials (unrolled, independent, coalesced), LDS-tree over rg.
__global__ void bn_fin_kernel(const float2* __restrict__ part, const float* __restrict__ g,
                              const float* __restrict__ be, float2* __restrict__ stats) {
  __shared__ float red_s[8][32];
  __shared__ float red_q[8][32];
  const int t = threadIdx.x;
  const int lc = t & 31, rg = t >> 5;
  const int c = blockIdx.x * 32 + lc;
  float s = 0.f, q = 0.f;
#pragma unroll
  for (int k = 0; k < 12; ++k) {
    float2 v = part[(size_t)(rg + 8 * k) * 512 + c];
    s += v.x; q += v.y;
  }
  red_s[rg][lc] = s; red_q[rg][lc] = q;
  __syncthreads();
  if (rg == 0) {
#pragma unroll
    for (int r = 1; r < 8; ++r) { s += red_s[r][lc]; q += red_q[r][lc]; }
    const float inv = 1.f / (float)N_NODES;
    float m = s * inv, var = q * inv - m * m;
    float sc = g[c] * rsqrtf(var + EPSV);
    stats[c] = make_float2(sc, be[c] - m * sc);
  }
}

// Fold BN1 into FFN1: bt_1[j][c] *= sc1[c] (in place);
// b1f[j] = b1[j] + sum_c ofs1[c] * bt_1[j][c].  256 blocks x 4 rows (1/wave).
__global__ void bn1_fold_kernel(u16* __restrict__ bt_1, const float* __restrict__ b1,
                                const float2* __restrict__ stats1, float* __restrict__ b1f) {
  const int tid = threadIdx.x, lane = tid & 63, wv = tid >> 6;
  const int j = blockIdx.x * 4 + wv;
  u16* row = bt_1 + (size_t)j * 512 + lane * 8;
  s16x8 v = *(const s16x8*)row;
  s16x8 o;
  float dot = 0.f;
#pragma unroll
  for (int t = 0; t < 8; ++t) {
    float2 st = stats1[lane * 8 + t];
    float w = bf2f((u16)v[t]);
    o[t] = (short)f2bf(w * st.x);
    dot += w * st.y;
  }
  *(s16x8*)row = o;
  dot += __shfl_xor(dot, 1);  dot += __shfl_xor(dot, 2);
  dot += __shfl_xor(dot, 4);  dot += __shfl_xor(dot, 8);
  dot += __shfl_xor(dot, 16); dot += __shfl_xor(dot, 32);
  if (lane == 0) b1f[j] = b1[j] + dot;
}

__global__ void bn_apply_f32_kernel(float* __restrict__ x, const float2* __restrict__ stats) {
  const int i = (blockIdx.x * 256 + threadIdx.x) * 4;
  float4 v = *(float4*)(x + i);
  const int c = i & 511;
  float2 sa = stats[c], sb = stats[c + 1], sc2 = stats[c + 2], sd = stats[c + 3];
  *(float4*)(x + i) = make_float4(v.x * sa.x + sa.y, v.y * sb.x + sb.y,
                                  v.z * sc2.x + sc2.y, v.w * sd.x + sd.y);
}

// ---------------------------------------------------------------- launch
extern "C" void kernel_launch(void* const* d_in, const int* in_sizes, int n_in,
                              void* d_out, int out_size, void* d_ws, size_t ws_size,
                              hipStream_t stream) {
  const float* h   = (const float*)d_in[0];
  const int* batch = (const int*)d_in[1];
  const float* Wq = (const float*)d_in[2];  const float* bq = (const float*)d_in[3];
  const float* Wk = (const float*)d_in[4];  const float* bk = (const float*)d_in[5];
  const float* Wv = (const float*)d_in[6];  const float* bv = (const float*)d_in[7];
  const float* Wo = (const float*)d_in[8];  const float* bo = (const float*)d_in[9];
  const float* g1 = (const float*)d_in[10]; const float* be1 = (const float*)d_in[11];
  const float* W1 = (const float*)d_in[12]; const float* b1v = (const float*)d_in[13];
  const float* W2 = (const float*)d_in[14]; const float* b2v = (const float*)d_in[15];
  const float* g2 = (const float*)d_in[16]; const float* be2 = (const float*)d_in[17];
  float* out = (float*)d_out;
  (void)in_sizes; (void)n_in; (void)out_size; (void)ws_size;

  char* ws = (char*)d_ws;
  size_t off = 0;
  auto alloc = [&](size_t bytes) -> void* {
    void* p = ws + off;
    off += (bytes + 255) & ~(size_t)255;
    return p;
  };
  int*    starts = (int*)alloc(17 * 4);
  float2* part1  = (float2*)alloc((size_t)96 * 512 * sizeof(float2));
  float2* part2  = (float2*)alloc((size_t)96 * 512 * sizeof(float2));
  float2* stats1 = (float2*)alloc(512 * sizeof(float2));
  float2* stats2 = (float2*)alloc(512 * sizeof(float2));
  float*  b1f    = (float*)alloc(1024 * sizeof(float));
  u16* bt_qkv = (u16*)alloc((size_t)1536 * 512 * 2);
  u16* bt_o   = (u16*)alloc((size_t)512 * 512 * 2);
  u16* bt_1   = (u16*)alloc((size_t)1024 * 512 * 2);
  u16* bt_2   = (u16*)alloc((size_t)512 * 1024 * 2);
  u16* A0  = (u16*)alloc((size_t)N_NODES * 512 * 2);          // h bf16; reused as av
  u16* qp  = (u16*)alloc((size_t)(N_NODES + 64) * 512 * 2);   // reused (with kp) as x2
  u16* kp  = (u16*)alloc((size_t)(N_NODES + 64) * 512 * 2);
  u16* vpb = (u16*)alloc((size_t)(N_NODES + 64) * 512 * 2);
  u16* x1b = (u16*)alloc((size_t)N_NODES * 512 * 2);          // pre-BN1 value (bf16)
  u16* av = A0;
  u16* x2 = qp;  // qp+kp = 12.7MB >= 12.6MB needed

  prep_kernel<<<5121, 256, 0, stream>>>(h, batch, Wq, Wk, Wv, Wo, W1, W2,
                                        bt_qkv, bt_o, bt_1, bt_2, A0, starts);
  gemm_kernel<128, 192, 0><<<dim3(8, 48), 256, 0, stream>>>(
      A0, bt_qkv, bq, bk, bv, nullptr, nullptr, nullptr, nullptr, qp, kp, vpb,
      nullptr, nullptr, N_NODES, 1536, 512);
  attn_kernel<<<NGRAPH * NHEAD * 8, 256, 0, stream>>>(qp, kp, vpb, starts, av);
  gemm_kernel<64, 128, 1><<<dim3(4, 96), 256, 0, stream>>>(
      av, bt_o, bo, nullptr, nullptr, h, nullptr, nullptr, part1,
      nullptr, nullptr, nullptr, nullptr, x1b, N_NODES, 512, 512);
  bn_fin_kernel<<<16, 256, 0, stream>>>(part1, g1, be1, stats1);
  bn1_fold_kernel<<<256, 256, 0, stream>>>(bt_1, b1v, stats1, b1f);
  gemm_kernel<128, 128, 2><<<dim3(8, 48), 256, 0, stream>>>(
      x1b, bt_1, b1f, nullptr, nullptr, nullptr, nullptr, nullptr, nullptr,
      nullptr, nullptr, nullptr, nullptr, x2, N_NODES, 1024, 512);
  gemm_kernel<64, 128, 3><<<dim3(4, 96), 256, 0, stream>>>(
      x2, bt_2, b2v, nullptr, nullptr, nullptr, x1b, stats1, part2,
      nullptr, nullptr, nullptr, out, nullptr, N_NODES, 512, 1024);
  bn_fin_kernel<<<16, 256, 0, stream>>>(part2, g2, be2, stats2);
  bn_apply_f32_kernel<<<3072, 256, 0, stream>>>(out, stats2);
}